// Round 11
// baseline (513.261 us; speedup 1.0000x reference)
//
#include <hip/hip_runtime.h>
#include <math.h>

#define B_ 8
#define N_ 2048
#define D_ 3
#define H_ 256
#define ND_ (N_*D_)     // 6144
#define BN_ (B_*N_)     // 16384

// ---------------- fused per-batch std (ddof=1) + pack + zero potentials ----------------
// R9 VERBATIM.
__global__ __launch_bounds__(256) void stdprep_kernel(const float* __restrict__ cloud,
    const float* __restrict__ noise,
    float4* __restrict__ x0p, float4* __restrict__ np4,
    float* __restrict__ f, float* __restrict__ g) {
  __shared__ float red[256];
  int b = blockIdx.x, tid = threadIdx.x;
  const float* p = cloud + (size_t)b * ND_;
  float s = 0.f;
  for (int i = tid; i < ND_; i += 256) s += p[i];
  red[tid] = s; __syncthreads();
  for (int off = 128; off > 0; off >>= 1) {
    if (tid < off) red[tid] += red[tid + off];
    __syncthreads();
  }
  float mean = red[0] / (float)ND_;
  __syncthreads();
  float ss = 0.f;
  for (int i = tid; i < ND_; i += 256) { float d = p[i] - mean; ss += d * d; }
  red[tid] = ss; __syncthreads();
  for (int off = 128; off > 0; off >>= 1) {
    if (tid < off) red[tid] += red[tid + off];
    __syncthreads();
  }
  float sd = sqrtf(red[0] / (float)(ND_ - 1));
  int base = b * N_;
  for (int i = tid; i < N_; i += 256) {
    int gi = base + i;
    float cx = cloud[3*gi] / sd, cy = cloud[3*gi+1] / sd, cz = cloud[3*gi+2] / sd;
    x0p[gi] = make_float4(cx, cy, cz, cx*cx + cy*cy + cz*cz);
    float ax = noise[3*gi], ay = noise[3*gi+1], az = noise[3*gi+2];
    np4[gi] = make_float4(ax, ay, az, ax*ax + ay*ay + az*az);
    f[gi] = 0.f; g[gi] = 0.f;
  }
}

// ---------------- one Sinkhorn half-iteration: ONE-PASS online LSE ----------------
// R9's two-pass kernel was secretly recompute-based: VGPR_Count=40 cannot hold
// the v[32]x2 arrays, so the compiler re-read LDS + recomputed pass 2
// (~2048 ds_read_b128/CU/dispatch ~ 10us DS -> the sticky 11.5us).
// Fix: branchless online softmax -> NO v-arrays, ONE tile sweep:
//   n = fmax(m,t); s = fma(s, exp2(m-n), exp2(t-n)); m = n
// (m=-inf start: exp2(-inf)=0, fmaf(0,0,1)=1 -> well-defined.)
// 8 waves x 4 rows = 32 rows/block, grid 512 (all resident, 2 blocks/CU),
// launch_bounds(512,8) pins <=64 VGPR (no arrays -> ~55, no spill).
// DS/CU/dispatch: 512 b128 (4x less). Cross-lane merge does the same
// rescale-combine. Not bit-identical to two-pass (same LSE value, different
// summation tree, ~1e-7 log2-domain deviation; tolerance is 2e-3).
// XCD-affine batch map kept. Lessons pinned: R5/R7 persistence >> dispatch
// chain; R3/R8 do not restructure the tail.
__global__ __launch_bounds__(512, 8) void lse_kernel(
    const float4* __restrict__ outer, const float4* __restrict__ inner,
    const float* __restrict__ pin, float* __restrict__ pout,
    float scl, float kk, float hh, float c1, float c2) {
  __shared__ float4 sP[N_];   // 32 KB: scaled coords + q
  int tid = threadIdx.x;
  int b = blockIdx.x & 7;                  // XCD-affine: batch == XCD id
  int rowBase = (blockIdx.x >> 3) << 5;    // 32 rows per block
  int base = b * N_;
  int wave = tid >> 6, lane = tid & 63;
  int r0 = base + rowBase + (wave << 2);   // 4 rows per wave
  // issue row loads early; they complete under the staging loop
  float4 A0 = outer[r0], A1 = outer[r0+1], A2 = outer[r0+2], A3 = outer[r0+3];
  for (int j = tid; j < N_; j += 512) {
    float4 p = inner[base + j];
    float q = kk * pin[base + j] - hh * p.w;
    sP[j] = make_float4(scl * p.x, scl * p.y, scl * p.z, q);
  }
  float a0x = scl*A0.x, a0y = scl*A0.y, a0z = scl*A0.z, rc0 = -hh*A0.w;
  float a1x = scl*A1.x, a1y = scl*A1.y, a1z = scl*A1.z, rc1 = -hh*A1.w;
  float a2x = scl*A2.x, a2y = scl*A2.y, a2z = scl*A2.z, rc2 = -hh*A2.w;
  float a3x = scl*A3.x, a3y = scl*A3.y, a3z = scl*A3.z, rc3 = -hh*A3.w;
  __syncthreads();
  float m0 = -INFINITY, m1 = -INFINITY, m2 = -INFINITY, m3 = -INFINITY;
  float s0 = 0.f, s1 = 0.f, s2 = 0.f, s3 = 0.f;
#pragma unroll
  for (int jj = 0; jj < 32; ++jj) {
    float4 p = sP[(jj << 6) + lane];
    float t0 = fmaf(p.x, a0x, p.w); t0 = fmaf(p.y, a0y, t0); t0 = fmaf(p.z, a0z, t0);
    float n0 = fmaxf(m0, t0);
    s0 = fmaf(s0, __builtin_amdgcn_exp2f(m0 - n0), __builtin_amdgcn_exp2f(t0 - n0));
    m0 = n0;
    float t1 = fmaf(p.x, a1x, p.w); t1 = fmaf(p.y, a1y, t1); t1 = fmaf(p.z, a1z, t1);
    float n1 = fmaxf(m1, t1);
    s1 = fmaf(s1, __builtin_amdgcn_exp2f(m1 - n1), __builtin_amdgcn_exp2f(t1 - n1));
    m1 = n1;
    float t2 = fmaf(p.x, a2x, p.w); t2 = fmaf(p.y, a2y, t2); t2 = fmaf(p.z, a2z, t2);
    float n2 = fmaxf(m2, t2);
    s2 = fmaf(s2, __builtin_amdgcn_exp2f(m2 - n2), __builtin_amdgcn_exp2f(t2 - n2));
    m2 = n2;
    float t3 = fmaf(p.x, a3x, p.w); t3 = fmaf(p.y, a3y, t3); t3 = fmaf(p.z, a3z, t3);
    float n3 = fmaxf(m3, t3);
    s3 = fmaf(s3, __builtin_amdgcn_exp2f(m3 - n3), __builtin_amdgcn_exp2f(t3 - n3));
    m3 = n3;
  }
  // cross-lane merge: (m,s) pairs combine with the same rescale rule
#pragma unroll
  for (int off = 32; off >= 1; off >>= 1) {
    float mo, so, nn;
    mo = __shfl_xor(m0, off, 64); so = __shfl_xor(s0, off, 64);
    nn = fmaxf(m0, mo);
    s0 = fmaf(s0, __builtin_amdgcn_exp2f(m0 - nn), so * __builtin_amdgcn_exp2f(mo - nn));
    m0 = nn;
    mo = __shfl_xor(m1, off, 64); so = __shfl_xor(s1, off, 64);
    nn = fmaxf(m1, mo);
    s1 = fmaf(s1, __builtin_amdgcn_exp2f(m1 - nn), so * __builtin_amdgcn_exp2f(mo - nn));
    m1 = nn;
    mo = __shfl_xor(m2, off, 64); so = __shfl_xor(s2, off, 64);
    nn = fmaxf(m2, mo);
    s2 = fmaf(s2, __builtin_amdgcn_exp2f(m2 - nn), so * __builtin_amdgcn_exp2f(mo - nn));
    m2 = nn;
    mo = __shfl_xor(m3, off, 64); so = __shfl_xor(s3, off, 64);
    nn = fmaxf(m3, mo);
    s3 = fmaf(s3, __builtin_amdgcn_exp2f(m3 - nn), so * __builtin_amdgcn_exp2f(mo - nn));
    m3 = nn;
  }
  if (lane == 0) {
    pout[r0]   = fmaf(c1, rc0 + m0 + __builtin_amdgcn_logf(s0), c2);
    pout[r0+1] = fmaf(c1, rc1 + m1 + __builtin_amdgcn_logf(s1), c2);
    pout[r0+2] = fmaf(c1, rc2 + m2 + __builtin_amdgcn_logf(s2), c2);
    pout[r0+3] = fmaf(c1, rc3 + m3 + __builtin_amdgcn_logf(s3), c2);
  }
}

// ---------------- fused argmin(sqdist - g) + gather + interp + MLP ----------------
// R9/R6 VERBATIM. Do NOT restructure (R3/R8: any deviation from this
// 49.6KB-LDS shape became an HBM victim, 100-160us).
__global__ __launch_bounds__(256) void assign_mlp_kernel(
    const float4* __restrict__ np4, const float4* __restrict__ x0p,
    const float* __restrict__ g, const float* __restrict__ t,
    const float* __restrict__ W1, const float* __restrict__ Wt,
    const float* __restrict__ b1, const float* __restrict__ W2,
    const float* __restrict__ b2, float* __restrict__ out) {
  __shared__ float4 sPts[N_];
  __shared__ float  sg[N_];
  __shared__ float  sW1[3*H_], sWt[H_], sb1[H_], sW2[H_*3], sb2[3];
  int tid = threadIdx.x;
  int b = blockIdx.x & 7;                  // XCD-affine
  int rowBase = (blockIdx.x >> 3) << 4;    // 16 rows per block
  int base = b * N_;
  for (int j = tid; j < N_; j += 256) { sPts[j] = x0p[base+j]; sg[j] = g[base+j]; }
  for (int i = tid; i < 3*H_; i += 256) { sW1[i] = W1[i]; sW2[i] = W2[i]; }
  if (tid < H_) { sWt[tid] = Wt[tid]; sb1[tid] = b1[tid]; }
  if (tid < 3) sb2[tid] = b2[tid];
  __syncthreads();
  int wave = tid >> 6, lane = tid & 63;
  int r0 = base + rowBase + (wave << 2);
  float4 A0 = np4[r0], A1 = np4[r0+1], A2 = np4[r0+2], A3 = np4[r0+3];
  float b0 = INFINITY, b1v = INFINITY, b2v = INFINITY, b3v = INFINITY;
  int i0 = 0, i1 = 0, i2 = 0, i3 = 0;
#pragma unroll
  for (int jj = 0; jj < 32; ++jj) {
    int j = (jj << 6) + lane;
    float4 p = sPts[j];
    float gj = sg[j];
    float d0 = A0.x*p.x + A0.y*p.y + A0.z*p.z;
    float v0 = fmaxf(A0.w + p.w - 2.0f*d0, 0.0f) - gj;
    if (v0 < b0) { b0 = v0; i0 = j; }         // strict < keeps lowest j per lane
    float d1 = A1.x*p.x + A1.y*p.y + A1.z*p.z;
    float v1 = fmaxf(A1.w + p.w - 2.0f*d1, 0.0f) - gj;
    if (v1 < b1v) { b1v = v1; i1 = j; }
    float d2 = A2.x*p.x + A2.y*p.y + A2.z*p.z;
    float v2 = fmaxf(A2.w + p.w - 2.0f*d2, 0.0f) - gj;
    if (v2 < b2v) { b2v = v2; i2 = j; }
    float d3 = A3.x*p.x + A3.y*p.y + A3.z*p.z;
    float v3 = fmaxf(A3.w + p.w - 2.0f*d3, 0.0f) - gj;
    if (v3 < b3v) { b3v = v3; i3 = j; }
  }
#pragma unroll
  for (int off = 32; off >= 1; off >>= 1) {
    float ov; int oi;
    ov = __shfl_xor(b0, off, 64);  oi = __shfl_xor(i0, off, 64);
    if (ov < b0 || (ov == b0 && oi < i0)) { b0 = ov; i0 = oi; }
    ov = __shfl_xor(b1v, off, 64); oi = __shfl_xor(i1, off, 64);
    if (ov < b1v || (ov == b1v && oi < i1)) { b1v = ov; i1 = oi; }
    ov = __shfl_xor(b2v, off, 64); oi = __shfl_xor(i2, off, 64);
    if (ov < b2v || (ov == b2v && oi < i2)) { b2v = ov; i2 = oi; }
    ov = __shfl_xor(b3v, off, 64); oi = __shfl_xor(i3, off, 64);
    if (ov < b3v || (ov == b3v && oi < i3)) { b3v = ov; i3 = oi; }
  }
  float tb = t[b];
  int idx[4] = {i0, i1, i2, i3};
  float4 Ar[4] = {A0, A1, A2, A3};
#pragma unroll
  for (int rr = 0; rr < 4; ++rr) {
    float4 A = Ar[rr];
    float4 xa = sPts[idx[rr]];
    float xtx = (1.0f - tb)*xa.x + tb*A.x;
    float xty = (1.0f - tb)*xa.y + tb*A.y;
    float xtz = (1.0f - tb)*xa.z + tb*A.z;
    float acc0 = 0.f, acc1 = 0.f, acc2 = 0.f;
#pragma unroll
    for (int hh = 0; hh < 4; ++hh) {
      int h = (hh << 6) + lane;
      float hv = xtx*sW1[h] + xty*sW1[H_+h] + xtz*sW1[2*H_+h] + tb*sWt[h] + sb1[h];
      hv = fmaxf(hv, 0.0f);
      acc0 += hv * sW2[3*h];
      acc1 += hv * sW2[3*h+1];
      acc2 += hv * sW2[3*h+2];
    }
#pragma unroll
    for (int off = 32; off >= 1; off >>= 1) {
      acc0 += __shfl_xor(acc0, off, 64);
      acc1 += __shfl_xor(acc1, off, 64);
      acc2 += __shfl_xor(acc2, off, 64);
    }
    if (lane == 0) {
      int gi = r0 + rr;
      out[3*gi]   = acc0 + sb2[0];
      out[3*gi+1] = acc1 + sb2[1];
      out[3*gi+2] = acc2 + sb2[2];
      out[3*BN_ + 3*gi]   = A.x - xa.x;
      out[3*BN_ + 3*gi+1] = A.y - xa.y;
      out[3*BN_ + 3*gi+2] = A.z - xa.z;
    }
  }
}

extern "C" void kernel_launch(void* const* d_in, const int* in_sizes, int n_in,
                              void* d_out, int out_size, void* d_ws, size_t ws_size,
                              hipStream_t stream) {
  (void)in_sizes; (void)n_in; (void)out_size; (void)ws_size;
  const float* cloud = (const float*)d_in[0];
  const float* noise = (const float*)d_in[1];
  const float* t     = (const float*)d_in[2];
  const float* W1    = (const float*)d_in[3];
  const float* Wt    = (const float*)d_in[4];
  const float* b1    = (const float*)d_in[5];
  const float* W2    = (const float*)d_in[6];
  const float* b2w   = (const float*)d_in[7];
  float* out = (float*)d_out;

  float* ws   = (float*)d_ws;
  float4* x0p = (float4*)(ws + 16);         // BN_ float4
  float4* np4 = (float4*)(ws + 16 + 4*BN_); // BN_ float4
  float* f    = ws + 16 + 8*BN_;            // BN_
  float* g    = f + BN_;                    // BN_

  stdprep_kernel<<<B_, 256, 0, stream>>>(cloud, noise, x0p, np4, f, g);

  const double LOG2E = 1.4426950408889634074;
  const double LN2   = 0.6931471805599453094;
  const double logw  = -log(2048.0);          // loga == logb == -log(N)
  const double l0 = log10(32.0), l1 = log10(1e-6);
  for (int kit = 0; kit < 14; ++kit) {
    // np.geomspace(32, 1e-6, 14) == 10**linspace(log10(32), -6, 14), cast fp32
    double epsd = pow(10.0, l0 + (l1 - l0) * ((double)kit / 13.0));
    float eps = (float)epsd;
    float kk  = (float)(LOG2E / (double)eps);
    float hh  = 0.5f * kk;
    float scl = sqrtf(kk);
    float c1  = (float)(-(double)eps * LN2);
    float c2  = (float)(-(double)eps * logw);
    // f = -eps*lse_j(logb + (g - C)/eps): rows = noise, inner = x0/g
    lse_kernel<<<B_*(N_/32), 512, 0, stream>>>(np4, x0p, g, f, scl, kk, hh, c1, c2);
    // g = -eps*lse_i(loga + (f - C)/eps): rows = x0, inner = noise/f
    lse_kernel<<<B_*(N_/32), 512, 0, stream>>>(x0p, np4, f, g, scl, kk, hh, c1, c2);
  }

  assign_mlp_kernel<<<B_*(N_/16), 256, 0, stream>>>(np4, x0p, g, t, W1, Wt, b1, W2, b2w, out);
}

// Round 12
// 389.022 us; speedup vs baseline: 1.3194x; 1.3194x over previous
//
#include <hip/hip_runtime.h>
#include <math.h>

#define B_ 8
#define N_ 2048
#define D_ 3
#define H_ 256
#define ND_ (N_*D_)     // 6144
#define BN_ (B_*N_)     // 16384

// ---------------- fused per-batch std (ddof=1) + pack + zero potentials ----------------
// R9 VERBATIM (measured 388.5us total).
__global__ __launch_bounds__(256) void stdprep_kernel(const float* __restrict__ cloud,
    const float* __restrict__ noise,
    float4* __restrict__ x0p, float4* __restrict__ np4,
    float* __restrict__ f, float* __restrict__ g) {
  __shared__ float red[256];
  int b = blockIdx.x, tid = threadIdx.x;
  const float* p = cloud + (size_t)b * ND_;
  float s = 0.f;
  for (int i = tid; i < ND_; i += 256) s += p[i];
  red[tid] = s; __syncthreads();
  for (int off = 128; off > 0; off >>= 1) {
    if (tid < off) red[tid] += red[tid + off];
    __syncthreads();
  }
  float mean = red[0] / (float)ND_;
  __syncthreads();
  float ss = 0.f;
  for (int i = tid; i < ND_; i += 256) { float d = p[i] - mean; ss += d * d; }
  red[tid] = ss; __syncthreads();
  for (int off = 128; off > 0; off >>= 1) {
    if (tid < off) red[tid] += red[tid + off];
    __syncthreads();
  }
  float sd = sqrtf(red[0] / (float)(ND_ - 1));
  int base = b * N_;
  for (int i = tid; i < N_; i += 256) {
    int gi = base + i;
    float cx = cloud[3*gi] / sd, cy = cloud[3*gi+1] / sd, cz = cloud[3*gi+2] / sd;
    x0p[gi] = make_float4(cx, cy, cz, cx*cx + cy*cy + cz*cz);
    float ax = noise[3*gi], ay = noise[3*gi+1], az = noise[3*gi+2];
    np4[gi] = make_float4(ax, ay, az, ax*ax + ay*ay + az*az);
    f[gi] = 0.f; g[gi] = 0.f;
  }
}

// ---------------- one Sinkhorn half-iteration (log2 domain) ----------------
// R6/R9 VERBATIM (best measured: 11.5us/dispatch, 388.5us total).
// Full lse evidence table (per-dispatch): register two-pass 11.6 (R0);
// remat two-pass full-occ 11.5 (R6/R9); explicit-recompute 23 (R2);
// one-pass online 16 (R11, 2x exp2 on quarter-rate trans pipe); persistent
// grid.sync 65/phase (R5); persistent batch-barriers 27/phase (R7).
// Two opposite designs tie at 11.5 -> balanced DS+VALU/trans+ramp bound.
__global__ __launch_bounds__(512, 4) void lse_kernel(
    const float4* __restrict__ outer, const float4* __restrict__ inner,
    const float* __restrict__ pin, float* __restrict__ pout,
    float scl, float kk, float hh, float c1, float c2) {
  __shared__ float4 sP[N_];   // 32 KB: scaled coords + q
  int tid = threadIdx.x;
  int b = blockIdx.x & 7;                  // XCD-affine: batch == XCD id
  int rowBase = (blockIdx.x >> 3) << 4;    // 16 rows per block
  int base = b * N_;
  for (int j = tid; j < N_; j += 512) {
    float4 p = inner[base + j];
    float q = kk * pin[base + j] - hh * p.w;
    sP[j] = make_float4(scl * p.x, scl * p.y, scl * p.z, q);
  }
  __syncthreads();
  int wave = tid >> 6, lane = tid & 63;
  int r0 = base + rowBase + (wave << 1);   // 2 rows per wave
  float4 A0 = outer[r0], A1 = outer[r0+1];
  float a0x = scl*A0.x, a0y = scl*A0.y, a0z = scl*A0.z, rc0 = -hh*A0.w;
  float a1x = scl*A1.x, a1y = scl*A1.y, a1z = scl*A1.z, rc1 = -hh*A1.w;
  float v0[32], v1[32];
  float m0 = -INFINITY, m1 = -INFINITY;
#pragma unroll
  for (int jj = 0; jj < 32; ++jj) {
    float4 p = sP[(jj << 6) + lane];
    float t0 = fmaf(p.x, a0x, p.w); t0 = fmaf(p.y, a0y, t0); t0 = fmaf(p.z, a0z, t0);
    v0[jj] = t0; m0 = fmaxf(m0, t0);
    float t1 = fmaf(p.x, a1x, p.w); t1 = fmaf(p.y, a1y, t1); t1 = fmaf(p.z, a1z, t1);
    v1[jj] = t1; m1 = fmaxf(m1, t1);
  }
#pragma unroll
  for (int off = 32; off >= 1; off >>= 1) {
    m0 = fmaxf(m0, __shfl_xor(m0, off, 64));
    m1 = fmaxf(m1, __shfl_xor(m1, off, 64));
  }
  float s0 = 0.f, s1 = 0.f;
#pragma unroll
  for (int jj = 0; jj < 32; ++jj) {
    s0 += __builtin_amdgcn_exp2f(v0[jj] - m0);
    s1 += __builtin_amdgcn_exp2f(v1[jj] - m1);
  }
#pragma unroll
  for (int off = 32; off >= 1; off >>= 1) {
    s0 += __shfl_xor(s0, off, 64);
    s1 += __shfl_xor(s1, off, 64);
  }
  if (lane == 0) {
    pout[r0]   = fmaf(c1, rc0 + m0 + __builtin_amdgcn_logf(s0), c2);
    pout[r0+1] = fmaf(c1, rc1 + m1 + __builtin_amdgcn_logf(s1), c2);
  }
}

// ---------------- fused argmin(sqdist - g) + gather + interp + MLP ----------------
// R6/R9 VERBATIM. Do NOT restructure (R3/R8: any deviation from this
// 49.6KB-LDS shape became an HBM victim, 100-160us; this shape measured
// 44.5/43.0/41.2/41.5us across R1/R4/R6/R9-R11).
__global__ __launch_bounds__(256) void assign_mlp_kernel(
    const float4* __restrict__ np4, const float4* __restrict__ x0p,
    const float* __restrict__ g, const float* __restrict__ t,
    const float* __restrict__ W1, const float* __restrict__ Wt,
    const float* __restrict__ b1, const float* __restrict__ W2,
    const float* __restrict__ b2, float* __restrict__ out) {
  __shared__ float4 sPts[N_];
  __shared__ float  sg[N_];
  __shared__ float  sW1[3*H_], sWt[H_], sb1[H_], sW2[H_*3], sb2[3];
  int tid = threadIdx.x;
  int b = blockIdx.x & 7;                  // XCD-affine
  int rowBase = (blockIdx.x >> 3) << 4;    // 16 rows per block
  int base = b * N_;
  for (int j = tid; j < N_; j += 256) { sPts[j] = x0p[base+j]; sg[j] = g[base+j]; }
  for (int i = tid; i < 3*H_; i += 256) { sW1[i] = W1[i]; sW2[i] = W2[i]; }
  if (tid < H_) { sWt[tid] = Wt[tid]; sb1[tid] = b1[tid]; }
  if (tid < 3) sb2[tid] = b2[tid];
  __syncthreads();
  int wave = tid >> 6, lane = tid & 63;
  int r0 = base + rowBase + (wave << 2);
  float4 A0 = np4[r0], A1 = np4[r0+1], A2 = np4[r0+2], A3 = np4[r0+3];
  float b0 = INFINITY, b1v = INFINITY, b2v = INFINITY, b3v = INFINITY;
  int i0 = 0, i1 = 0, i2 = 0, i3 = 0;
#pragma unroll
  for (int jj = 0; jj < 32; ++jj) {
    int j = (jj << 6) + lane;
    float4 p = sPts[j];
    float gj = sg[j];
    float d0 = A0.x*p.x + A0.y*p.y + A0.z*p.z;
    float v0 = fmaxf(A0.w + p.w - 2.0f*d0, 0.0f) - gj;
    if (v0 < b0) { b0 = v0; i0 = j; }         // strict < keeps lowest j per lane
    float d1 = A1.x*p.x + A1.y*p.y + A1.z*p.z;
    float v1 = fmaxf(A1.w + p.w - 2.0f*d1, 0.0f) - gj;
    if (v1 < b1v) { b1v = v1; i1 = j; }
    float d2 = A2.x*p.x + A2.y*p.y + A2.z*p.z;
    float v2 = fmaxf(A2.w + p.w - 2.0f*d2, 0.0f) - gj;
    if (v2 < b2v) { b2v = v2; i2 = j; }
    float d3 = A3.x*p.x + A3.y*p.y + A3.z*p.z;
    float v3 = fmaxf(A3.w + p.w - 2.0f*d3, 0.0f) - gj;
    if (v3 < b3v) { b3v = v3; i3 = j; }
  }
#pragma unroll
  for (int off = 32; off >= 1; off >>= 1) {
    float ov; int oi;
    ov = __shfl_xor(b0, off, 64);  oi = __shfl_xor(i0, off, 64);
    if (ov < b0 || (ov == b0 && oi < i0)) { b0 = ov; i0 = oi; }
    ov = __shfl_xor(b1v, off, 64); oi = __shfl_xor(i1, off, 64);
    if (ov < b1v || (ov == b1v && oi < i1)) { b1v = ov; i1 = oi; }
    ov = __shfl_xor(b2v, off, 64); oi = __shfl_xor(i2, off, 64);
    if (ov < b2v || (ov == b2v && oi < i2)) { b2v = ov; i2 = oi; }
    ov = __shfl_xor(b3v, off, 64); oi = __shfl_xor(i3, off, 64);
    if (ov < b3v || (ov == b3v && oi < i3)) { b3v = ov; i3 = oi; }
  }
  float tb = t[b];
  int idx[4] = {i0, i1, i2, i3};
  float4 Ar[4] = {A0, A1, A2, A3};
#pragma unroll
  for (int rr = 0; rr < 4; ++rr) {
    float4 A = Ar[rr];
    float4 xa = sPts[idx[rr]];
    float xtx = (1.0f - tb)*xa.x + tb*A.x;
    float xty = (1.0f - tb)*xa.y + tb*A.y;
    float xtz = (1.0f - tb)*xa.z + tb*A.z;
    float acc0 = 0.f, acc1 = 0.f, acc2 = 0.f;
#pragma unroll
    for (int hh = 0; hh < 4; ++hh) {
      int h = (hh << 6) + lane;
      float hv = xtx*sW1[h] + xty*sW1[H_+h] + xtz*sW1[2*H_+h] + tb*sWt[h] + sb1[h];
      hv = fmaxf(hv, 0.0f);
      acc0 += hv * sW2[3*h];
      acc1 += hv * sW2[3*h+1];
      acc2 += hv * sW2[3*h+2];
    }
#pragma unroll
    for (int off = 32; off >= 1; off >>= 1) {
      acc0 += __shfl_xor(acc0, off, 64);
      acc1 += __shfl_xor(acc1, off, 64);
      acc2 += __shfl_xor(acc2, off, 64);
    }
    if (lane == 0) {
      int gi = r0 + rr;
      out[3*gi]   = acc0 + sb2[0];
      out[3*gi+1] = acc1 + sb2[1];
      out[3*gi+2] = acc2 + sb2[2];
      out[3*BN_ + 3*gi]   = A.x - xa.x;
      out[3*BN_ + 3*gi+1] = A.y - xa.y;
      out[3*BN_ + 3*gi+2] = A.z - xa.z;
    }
  }
}

extern "C" void kernel_launch(void* const* d_in, const int* in_sizes, int n_in,
                              void* d_out, int out_size, void* d_ws, size_t ws_size,
                              hipStream_t stream) {
  (void)in_sizes; (void)n_in; (void)out_size; (void)ws_size;
  const float* cloud = (const float*)d_in[0];
  const float* noise = (const float*)d_in[1];
  const float* t     = (const float*)d_in[2];
  const float* W1    = (const float*)d_in[3];
  const float* Wt    = (const float*)d_in[4];
  const float* b1    = (const float*)d_in[5];
  const float* W2    = (const float*)d_in[6];
  const float* b2w   = (const float*)d_in[7];
  float* out = (float*)d_out;

  float* ws   = (float*)d_ws;
  float4* x0p = (float4*)(ws + 16);         // BN_ float4
  float4* np4 = (float4*)(ws + 16 + 4*BN_); // BN_ float4
  float* f    = ws + 16 + 8*BN_;            // BN_
  float* g    = f + BN_;                    // BN_

  stdprep_kernel<<<B_, 256, 0, stream>>>(cloud, noise, x0p, np4, f, g);

  const double LOG2E = 1.4426950408889634074;
  const double LN2   = 0.6931471805599453094;
  const double logw  = -log(2048.0);          // loga == logb == -log(N)
  const double l0 = log10(32.0), l1 = log10(1e-6);
  for (int kit = 0; kit < 14; ++kit) {
    // np.geomspace(32, 1e-6, 14) == 10**linspace(log10(32), -6, 14), cast fp32
    double epsd = pow(10.0, l0 + (l1 - l0) * ((double)kit / 13.0));
    float eps = (float)epsd;
    float kk  = (float)(LOG2E / (double)eps);
    float hh  = 0.5f * kk;
    float scl = sqrtf(kk);
    float c1  = (float)(-(double)eps * LN2);
    float c2  = (float)(-(double)eps * logw);
    // f = -eps*lse_j(logb + (g - C)/eps): rows = noise, inner = x0/g
    lse_kernel<<<B_*(N_/16), 512, 0, stream>>>(np4, x0p, g, f, scl, kk, hh, c1, c2);
    // g = -eps*lse_i(loga + (f - C)/eps): rows = x0, inner = noise/f
    lse_kernel<<<B_*(N_/16), 512, 0, stream>>>(x0p, np4, f, g, scl, kk, hh, c1, c2);
  }

  assign_mlp_kernel<<<B_*(N_/16), 256, 0, stream>>>(np4, x0p, g, t, W1, Wt, b1, W2, b2w, out);
}